// Round 5
// baseline (883.265 us; speedup 1.0000x reference)
//
#include <hip/hip_runtime.h>
#include <hip/hip_bf16.h>
#include <math.h>

#define NT 16384
#define DM 1024
#define NE 4

typedef __attribute__((ext_vector_type(8))) short short8;  // 8 bf16 (4 VGPRs)
typedef __attribute__((ext_vector_type(4))) float f32x4;

// global -> LDS direct DMA, 16B/lane; LDS dest = wave-uniform base + lane*16
#define GLDS(g, l)                                                        \
  __builtin_amdgcn_global_load_lds(                                       \
      (const __attribute__((address_space(1))) void*)(g),                 \
      (__attribute__((address_space(3))) void*)(l), 16, 0, 0)

__device__ __forceinline__ float bf2f(short h) {
    union { unsigned u; float f; } v;
    v.u = ((unsigned)(unsigned short)h) << 16;
    return v.f;
}

// ============ dtype detection: bf16 vs fp32, from bit statistics of x ========
__global__ __launch_bounds__(256) void detect_kernel(
    const unsigned int* __restrict__ xw, int* __restrict__ flag)
{
    __shared__ int red[4];
    const int t = threadIdx.x;
    int cnt = 0;
    #pragma unroll 4
    for (int i = 0; i < 64; ++i) {
        unsigned w = xw[t * 64 + i];
        unsigned e0 = (w >> 7) & 0xFFu;
        cnt += (e0 >= 100u && e0 <= 150u) ? 1 : 0;
    }
    #pragma unroll
    for (int o = 32; o > 0; o >>= 1) cnt += __shfl_xor(cnt, o);
    if ((t & 63) == 0) red[t >> 6] = cnt;
    __syncthreads();
    if (t == 0) {
        int tot = red[0] + red[1] + red[2] + red[3];
        *flag = (tot > 8192) ? 1 : 0;   // 1 = bf16 inputs, 0 = fp32 inputs
    }
}

// ============ zero idx lists + counts (ws re-poisoned before every call) =====
__global__ __launch_bounds__(256) void init_kernel(
    int* __restrict__ counts, int* __restrict__ idx)
{
    const int t = blockIdx.x * 256 + threadIdx.x;   // 256 blocks -> 65536 = NE*NT
    idx[t] = 0;
    if (t < NE) counts[t] = 0;
}

// ====== fused big converts: x, w1, w2 fp32->bf16 in ONE kernel ==============
__global__ __launch_bounds__(256) void convert_all_kernel(
    const float* __restrict__ x, const float* __restrict__ w1,
    const float* __restrict__ w2,
    short* __restrict__ xb, short* __restrict__ w1b, short* __restrict__ w2b,
    const int* __restrict__ flag)
{
    if (*flag) return;                   // bf16 inputs: consumers read raw ptr
    const int n1 = NT * DM / 4;          // float4 units
    const int n2 = NE * 2 * DM * DM / 4;
    const int total = n1 + 2 * n2;
    const int stride = gridDim.x * blockDim.x;
    for (int i = blockIdx.x * blockDim.x + threadIdx.x; i < total; i += stride) {
        const float4* s; short* d; int j;
        if (i < n1)           { s = (const float4*)x;  d = xb;  j = i; }
        else if (i < n1 + n2) { s = (const float4*)w1; d = w1b; j = i - n1; }
        else                  { s = (const float4*)w2; d = w2b; j = i - n1 - n2; }
        float4 v = s[j];
        __hip_bfloat16 b0 = __float2bfloat16(v.x);
        __hip_bfloat16 b1 = __float2bfloat16(v.y);
        __hip_bfloat16 b2 = __float2bfloat16(v.z);
        __hip_bfloat16 b3 = __float2bfloat16(v.w);
        short4 o;
        o.x = *(short*)&b0; o.y = *(short*)&b1;
        o.z = *(short*)&b2; o.w = *(short*)&b3;
        *(short4*)(d + (size_t)j * 4) = o;
    }
}

// ============ small converts fused: b1(8192) b2(4096) gamma(4096) beta(4096) =
__global__ __launch_bounds__(256) void convert_small_kernel(
    const void* __restrict__ b1, const void* __restrict__ b2,
    const void* __restrict__ ga, const void* __restrict__ be,
    short* __restrict__ b1d, short* __restrict__ b2d,
    short* __restrict__ gad, short* __restrict__ bed,
    const int* __restrict__ flag)
{
    const int isbf = *flag;
    const int t = blockIdx.x * 256 + threadIdx.x;     // 80 blocks = 20480 threads
    const void* src; short* dst; int i;
    if (t < 8192)      { src = b1; dst = b1d; i = t; }
    else if (t < 12288){ src = b2; dst = b2d; i = t - 8192; }
    else if (t < 16384){ src = ga; dst = gad; i = t - 12288; }
    else               { src = be; dst = bed; i = t - 16384; }
    short v;
    if (isbf) v = ((const short*)src)[i];
    else {
        __hip_bfloat16 b = __float2bfloat16(((const float*)src)[i]);
        v = *(short*)&b;
    }
    dst[i] = v;
}

// ======= gate: fp64-acc scores on RAW inputs -> comb[NT,4] + choice[NT] ======
__global__ __launch_bounds__(256) void gate_kernel(
    const void* __restrict__ x, const void* __restrict__ gw,
    float* __restrict__ comb, int* __restrict__ choice,
    const int* __restrict__ flag)
{
    const int lane  = threadIdx.x & 63;
    const int token = blockIdx.x * 4 + (threadIdx.x >> 6);
    double s0 = 0., s1 = 0., s2 = 0., s3 = 0.;
    if (*flag) {
        const short8* xr = (const short8*)((const short*)x + (size_t)token * DM);
        const short8* g0 = (const short8*)((const short*)gw + 0 * DM);
        const short8* g1 = (const short8*)((const short*)gw + 1 * DM);
        const short8* g2 = (const short8*)((const short*)gw + 2 * DM);
        const short8* g3 = (const short8*)((const short*)gw + 3 * DM);
        #pragma unroll
        for (int c = 0; c < 2; ++c) {
            short8 xv = xr[c * 64 + lane];
            short8 a0 = g0[c * 64 + lane], a1 = g1[c * 64 + lane];
            short8 a2 = g2[c * 64 + lane], a3 = g3[c * 64 + lane];
            #pragma unroll
            for (int j = 0; j < 8; ++j) {
                double xd = (double)bf2f(xv[j]);
                s0 += xd * (double)bf2f(a0[j]);
                s1 += xd * (double)bf2f(a1[j]);
                s2 += xd * (double)bf2f(a2[j]);
                s3 += xd * (double)bf2f(a3[j]);
            }
        }
    } else {
        const float4* xr = (const float4*)((const float*)x + (size_t)token * DM);
        const float4* g0 = (const float4*)((const float*)gw + 0 * DM);
        const float4* g1 = (const float4*)((const float*)gw + 1 * DM);
        const float4* g2 = (const float4*)((const float*)gw + 2 * DM);
        const float4* g3 = (const float4*)((const float*)gw + 3 * DM);
        #pragma unroll
        for (int c = 0; c < 4; ++c) {
            float4 xv = xr[c * 64 + lane];
            float4 a0 = g0[c * 64 + lane], a1 = g1[c * 64 + lane];
            float4 a2 = g2[c * 64 + lane], a3 = g3[c * 64 + lane];
            s0 += (double)xv.x * a0.x + (double)xv.y * a0.y + (double)xv.z * a0.z + (double)xv.w * a0.w;
            s1 += (double)xv.x * a1.x + (double)xv.y * a1.y + (double)xv.z * a1.z + (double)xv.w * a1.w;
            s2 += (double)xv.x * a2.x + (double)xv.y * a2.y + (double)xv.z * a2.z + (double)xv.w * a2.w;
            s3 += (double)xv.x * a3.x + (double)xv.y * a3.y + (double)xv.z * a3.z + (double)xv.w * a3.w;
        }
    }
    #pragma unroll
    for (int off = 32; off > 0; off >>= 1) {
        s0 += __shfl_xor(s0, off);
        s1 += __shfl_xor(s1, off);
        s2 += __shfl_xor(s2, off);
        s3 += __shfl_xor(s3, off);
    }
    if (lane == 0) {
        double s[4] = {s0, s1, s2, s3};
        int i1 = 0;
        #pragma unroll
        for (int e = 1; e < 4; ++e) if (s[e] > s[i1]) i1 = e;  // ties -> lowest idx
        int i2 = -1;
        #pragma unroll
        for (int e = 0; e < 4; ++e) {
            if (e == i1) continue;
            if (i2 < 0 || s[e] > s[i2]) i2 = e;
        }
        float e2 = expf((float)(s[i2] - s[i1]));
        float wa = 1.0f / (1.0f + e2);
        float wb = e2 * wa;
        float* cr = comb + (size_t)token * 4;
        #pragma unroll
        for (int e = 0; e < 4; ++e)
            cr[e] = (e == i1) ? wa : ((e == i2) ? wb : 0.0f);
        choice[token] = i1 | (i2 << 8);
    }
}

// ======= route: block-aggregated compaction + per-token list positions =======
__global__ __launch_bounds__(256) void route_kernel(
    const int* __restrict__ choice, int* __restrict__ counts,
    int* __restrict__ idx, int* __restrict__ pos)
{
    __shared__ int T[4][8];     // [wave][k*4+e] per-wave counts
    __shared__ int base[4];
    const int tid = threadIdx.x, w = tid >> 6, lane = tid & 63;
    const int t = blockIdx.x * 256 + tid;
    const int c = choice[t];
    const int e0 = c & 0xFF, e1 = (c >> 8) & 0xFF;
    const unsigned long long lt = ((unsigned long long)1 << lane) - 1;
    int rank0 = 0, rank1 = 0;
    #pragma unroll
    for (int e = 0; e < 4; ++e) {
        unsigned long long m0 = __ballot(e0 == e);
        unsigned long long m1 = __ballot(e1 == e);
        if (e0 == e) rank0 = __popcll(m0 & lt);
        if (e1 == e) rank1 = __popcll(m1 & lt);
        if (lane == 0) { T[w][e] = __popcll(m0); T[w][4 + e] = __popcll(m1); }
    }
    __syncthreads();
    if (tid < 4) {
        int tot = 0;
        #pragma unroll
        for (int w2 = 0; w2 < 4; ++w2) tot += T[w2][tid] + T[w2][4 + tid];
        base[tid] = atomicAdd(&counts[tid], tot);
    }
    __syncthreads();
    int off0 = base[e0], off1 = base[e1];
    #pragma unroll
    for (int w2 = 0; w2 < 4; ++w2) {
        if (w2 < w) off0 += T[w2][e0];
        off1 += T[w2][e1];                   // all k=0 entries precede k=1
        if (w2 < w) off1 += T[w2][4 + e1];
    }
    const int p0 = off0 + rank0;
    const int p1 = off1 + rank1;
    idx[e0 * NT + p0] = t;
    idx[e1 * NT + p1] = t;
    pos[t] = p0 | (p1 << 16);                // position of token in both lists
}

// ====== BK=32 tiled GEMM, C = Asel @ B[N,K]^T + bias =========================
// BM=256, BN in {256,128}. 8 waves (2Mx4N), double-buffered LDS:
//   gemm1 64 KiB -> 2 blocks/CU; gemm2 48 KiB -> 3 blocks/CU. Cross-block
//   overlap (m114) fills barrier drains that 1-blk/CU lockstep exposed.
// T2 swizzle for 64B rows: slot = quad ^ ((row>>1)&3); source pre-XOR
//   (tid&3)^((tid>>3)&3); balanced 8 lanes per 4-bank span (conflict-free).
// T4 counted vmcnt(NLD): prefetch of tile t+1 stays in flight across barrier.
// Rarg==0: full mode (single dispatch, h/z at global compacted prefix rows)
// Rarg>0 : chunked mode (h rows at e*Rarg + local; z at prefix + c0 + local)
// Rarg<0 : per-expert fallback (h/z chunk-local)
// EPI 0: A rows gathered via idx (x), out bf16 = gelu_exact(acc+bias)  -> h
// EPI 1: A dense rows (h),            out f32  = acc+bias              -> z
template <int EPI, int BN>
__global__ __launch_bounds__(512, 2) void gemm32(
    const short* __restrict__ Araw, const short* __restrict__ Acvt,
    const short* __restrict__ Braw, const short* __restrict__ Bcvt,
    const short* __restrict__ biasAll,       // bf16 bits, [NE][N]
    void* __restrict__ Cout,
    const int* __restrict__ idxAll,          // [NE][NT]
    const int* __restrict__ counts,
    int c0, int N, int K, const int* __restrict__ flag,
    int eArg, int Rarg)
{
    constexpr int WTM = 128;                 // per-wave M
    constexpr int WTN = BN / 4;              // 64 or 32
    constexpr int MT  = 8;
    constexpr int NTt = WTN / 16;            // 4 or 2
    constexpr int BCH = BN / 128;            // B staging units (128 rows each)

    // bijective XCD-chunk remap (m204): contiguous grid chunk per XCD,
    // expert (z) slowest -> one expert's weight panel per 2 XCDs.
    int bx, by, bz;
    {
        int lid = (int)blockIdx.x +
                  (int)gridDim.x * ((int)blockIdx.y + (int)gridDim.y * (int)blockIdx.z);
        const int nwg = (int)(gridDim.x * gridDim.y * gridDim.z);
        if (Rarg >= 0 && (nwg & 7) == 0) {
            const int q = nwg >> 3;
            lid = (lid & 7) * q + (lid >> 3);
        }
        bx = lid % (int)gridDim.x;
        const int rem = lid / (int)gridDim.x;
        by = rem % (int)gridDim.y;
        bz = rem / (int)gridDim.y;
    }

    const int e    = (Rarg < 0) ? eArg : bz;
    const int cnt  = counts[e] - c0;
    const int rowc = by * 256;               // local row of this block
    if (rowc >= cnt) return;                 // block-uniform early exit

    int hRow0 = 0, zRow0 = 0;
    if (Rarg >= 0) {
        int pre = 0;
        #pragma unroll
        for (int i = 0; i < NE; ++i) pre += (i < e) ? counts[i] : 0;
        zRow0 = pre + c0;
        hRow0 = (Rarg == 0) ? pre : e * Rarg;   // full: global-compacted h
    }

    const short* A = (*flag) ? Araw : Acvt;  // EPI==1: both point at h
    const short* B = ((*flag) ? Braw : Bcvt) + (size_t)e * 2 * DM * DM;
    const short* bias = biasAll + (size_t)e * N;

    __shared__ __align__(16) short sA[2][2 * 4096];      // 2 units x 128r x 32k
    __shared__ __align__(16) short sB[2][BCH * 4096];

    const int tid  = threadIdx.x;            // 0..511
    const int wid  = tid >> 6;               // 0..7
    const int col0 = bx * BN;
    const int wm = wid >> 2, wn = wid & 3;
    const int quad = (tid & 63) >> 4;
    const int mrow = tid & 15;

    // staging unit u: rows [u*128, u*128+128) x 32 k; thread -> row u*128+tid/4,
    // k8-slot tid&3. Source pre-swizzled: chunk (tid&3)^((tid>>3)&3).
    const int scol = (((tid & 3) ^ ((tid >> 3) & 3)) * 8);
    const short* gA[2];
    const short* gB[BCH];
    #pragma unroll
    for (int i = 0; i < 2; ++i) {
        const int lr = i * 128 + (tid >> 2);
        size_t grow;
        if (EPI == 0) grow = (size_t)idxAll[(size_t)e * NT + c0 + rowc + lr]; // zero-padded
        else          grow = (size_t)(hRow0 + rowc + lr);
        gA[i] = A + grow * (size_t)K + scol;
    }
    #pragma unroll
    for (int j = 0; j < BCH; ++j)
        gB[j] = B + (size_t)(col0 + j * 128 + (tid >> 2)) * K + scol;

    f32x4 acc[MT][NTt];
    #pragma unroll
    for (int m = 0; m < MT; ++m)
        #pragma unroll
        for (int n = 0; n < NTt; ++n)
            acc[m][n] = (f32x4){0.f, 0.f, 0.f, 0.f};

    auto stage = [&](int buf, int k0) {
        #pragma unroll
        for (int i = 0; i < 2; ++i)   GLDS(gA[i] + k0, &sA[buf][i * 4096] + wid * 512);
        #pragma unroll
        for (int j = 0; j < BCH; ++j) GLDS(gB[j] + k0, &sB[buf][j * 4096] + wid * 512);
    };

    const int boff = ((quad ^ ((mrow >> 1) & 3)) << 4);  // read-side slot (bytes)

    const int ntiles = K / 32;
    stage(0, 0);
    int cur = 0;
    for (int t = 0; t < ntiles; ++t) {
        if (t + 1 < ntiles) {
            stage(cur ^ 1, (t + 1) * 32);    // next tile stays in flight
            if (BCH == 2)
                asm volatile("s_waitcnt vmcnt(4)" ::: "memory");
            else
                asm volatile("s_waitcnt vmcnt(3)" ::: "memory");
        } else {
            asm volatile("s_waitcnt vmcnt(0)" ::: "memory");
        }
        __builtin_amdgcn_sched_barrier(0);
        __builtin_amdgcn_s_barrier();        // tile t fully visible
        const char* sAc = (const char*)&sA[cur][0];
        const char* sBc = (const char*)&sB[cur][0];
        short8 a[MT], b[NTt];
        #pragma unroll
        for (int m = 0; m < MT; ++m)
            a[m] = *(const short8*)(sAc + (wm * WTM + m * 16 + mrow) * 64 + boff);
        #pragma unroll
        for (int n = 0; n < NTt; ++n)
            b[n] = *(const short8*)(sBc + (wn * WTN + n * 16 + mrow) * 64 + boff);
        #pragma unroll
        for (int m = 0; m < MT; ++m)
            #pragma unroll
            for (int n = 0; n < NTt; ++n)
                acc[m][n] = __builtin_amdgcn_mfma_f32_16x16x32_bf16(
                    a[m], b[n], acc[m][n], 0, 0, 0);
        asm volatile("s_waitcnt lgkmcnt(0)" ::: "memory");
        __builtin_amdgcn_sched_barrier(0);
        __builtin_amdgcn_s_barrier();        // reads of buf[cur] closed
        cur ^= 1;
    }

    // epilogue: C/D layout col=lane&15, row=quad*4+reg (m89-verified)
    #pragma unroll
    for (int m = 0; m < MT; ++m) {
        #pragma unroll
        for (int n = 0; n < NTt; ++n) {
            const int col = col0 + wn * WTN + n * 16 + mrow;
            const float bval = bf2f(bias[col]);
            #pragma unroll
            for (int i = 0; i < 4; ++i) {
                const int lrow = rowc + wm * WTM + m * 16 + quad * 4 + i;
                if (lrow < cnt) {
                    float v = acc[m][n][i] + bval;
                    if (EPI == 0) {
                        v = 0.5f * v * (1.0f + erff(v * 0.70710678118654752f));
                        ((__hip_bfloat16*)Cout)[(size_t)(hRow0 + lrow) * N + col] =
                            __float2bfloat16(v);
                    } else {
                        ((float*)Cout)[(size_t)(zRow0 + lrow) * N + col] = v;
                    }
                }
            }
        }
    }
}

// ====== fused LN over BOTH experts of a token: y = w0*LN(z0+x) + w1*LN(z1+x) =
__global__ __launch_bounds__(256) void ln_fused_kernel(
    const float* __restrict__ z,               // [2*NT, DM] fp32, prefix layout
    const void* __restrict__ xraw,             // [NT, DM] raw input (bf16/fp32)
    const float* __restrict__ comb,            // [NT, 4]
    const int* __restrict__ choice,            // [NT] packed (i1 | i2<<8)
    const int* __restrict__ pos,               // [NT] packed (p0 | p1<<16)
    const short* __restrict__ gammaAll,        // bf16 bits [NE][DM]
    const short* __restrict__ betaAll,
    void* __restrict__ y,                      // [NT, DM] bf16 or fp32
    const int* __restrict__ counts, const int* __restrict__ flag)
{
    const int isbf = *flag;
    const int lane = threadIdx.x & 63;
    const int t = blockIdx.x * 4 + (threadIdx.x >> 6);

    const int ca = counts[0], cb = counts[1], cc = counts[2];
    const int ch = choice[t];
    const int e0 = ch & 0xFF, e1 = (ch >> 8) & 0xFF;
    const int pp = pos[t];
    const int p0 = pp & 0xFFFF, p1 = (pp >> 16) & 0xFFFF;
    const int b0r = (e0 > 0 ? ca : 0) + (e0 > 1 ? cb : 0) + (e0 > 2 ? cc : 0);
    const int b1r = (e1 > 0 ? ca : 0) + (e1 > 1 ? cb : 0) + (e1 > 2 ? cc : 0);
    const float w0 = comb[(size_t)t * 4 + e0];
    const float w1 = comb[(size_t)t * 4 + e1];

    const f32x4* z0r = (const f32x4*)(z + (size_t)(b0r + p0) * DM);
    const f32x4* z1r = (const f32x4*)(z + (size_t)(b1r + p1) * DM);

    f32x4 v0[4], v1[4];
    float s0 = 0.f, q0 = 0.f, s1 = 0.f, q1 = 0.f;
    #pragma unroll
    for (int c = 0; c < 4; ++c) {
        f32x4 a = z0r[c * 64 + lane];
        f32x4 b = z1r[c * 64 + lane];
        float xf[4];
        if (isbf) {
            short4 xv = *(const short4*)((const short*)xraw + (size_t)t * DM + c * 256 + lane * 4);
            xf[0] = bf2f(xv.x); xf[1] = bf2f(xv.y); xf[2] = bf2f(xv.z); xf[3] = bf2f(xv.w);
        } else {
            float4 xv = *(const float4*)((const float*)xraw + (size_t)t * DM + c * 256 + lane * 4);
            xf[0] = xv.x; xf[1] = xv.y; xf[2] = xv.z; xf[3] = xv.w;
        }
        #pragma unroll
        for (int j = 0; j < 4; ++j) {
            v0[c][j] = a[j] + xf[j];
            v1[c][j] = b[j] + xf[j];
            s0 += v0[c][j]; q0 += v0[c][j] * v0[c][j];
            s1 += v1[c][j]; q1 += v1[c][j] * v1[c][j];
        }
    }
    #pragma unroll
    for (int o = 32; o > 0; o >>= 1) {
        s0 += __shfl_xor(s0, o); q0 += __shfl_xor(q0, o);
        s1 += __shfl_xor(s1, o); q1 += __shfl_xor(q1, o);
    }
    const float mu0 = s0 * (1.0f / DM);
    const float r0  = rsqrtf(fmaxf(q0 * (1.0f / DM) - mu0 * mu0, 0.0f) + 1e-6f);
    const float mu1 = s1 * (1.0f / DM);
    const float r1  = rsqrtf(fmaxf(q1 * (1.0f / DM) - mu1 * mu1, 0.0f) + 1e-6f);

    #pragma unroll
    for (int c = 0; c < 4; ++c) {
        const int id = c * 256 + lane * 4;
        short4 g0v  = *(const short4*)(gammaAll + (size_t)e0 * DM + id);
        short4 be0v = *(const short4*)(betaAll  + (size_t)e0 * DM + id);
        short4 g1v  = *(const short4*)(gammaAll + (size_t)e1 * DM + id);
        short4 be1v = *(const short4*)(betaAll  + (size_t)e1 * DM + id);
        const float g0f[4]  = {bf2f(g0v.x),  bf2f(g0v.y),  bf2f(g0v.z),  bf2f(g0v.w)};
        const float b0f[4]  = {bf2f(be0v.x), bf2f(be0v.y), bf2f(be0v.z), bf2f(be0v.w)};
        const float g1f[4]  = {bf2f(g1v.x),  bf2f(g1v.y),  bf2f(g1v.z),  bf2f(g1v.w)};
        const float b1f[4]  = {bf2f(be1v.x), bf2f(be1v.y), bf2f(be1v.z), bf2f(be1v.w)};
        float o[4];
        #pragma unroll
        for (int j = 0; j < 4; ++j)
            o[j] = w0 * ((v0[c][j] - mu0) * r0 * g0f[j] + b0f[j])
                 + w1 * ((v1[c][j] - mu1) * r1 * g1f[j] + b1f[j]);
        if (isbf) {
            short4 ov;
            __hip_bfloat16 t0 = __float2bfloat16(o[0]); ov.x = *(short*)&t0;
            __hip_bfloat16 t1 = __float2bfloat16(o[1]); ov.y = *(short*)&t1;
            __hip_bfloat16 t2 = __float2bfloat16(o[2]); ov.z = *(short*)&t2;
            __hip_bfloat16 t3 = __float2bfloat16(o[3]); ov.w = *(short*)&t3;
            *(short4*)((short*)y + (size_t)t * DM + id) = ov;
        } else {
            float4 ov = {o[0], o[1], o[2], o[3]};
            *(float4*)((float*)y + (size_t)t * DM + id) = ov;
        }
    }
}

// ====== fallback LN (per-expert, accumulate) — chunked path only =============
__global__ __launch_bounds__(256) void ln_kernel(
    const float* __restrict__ z, const void* __restrict__ xraw,
    const float* __restrict__ comb, const int* __restrict__ choice,
    const __hip_bfloat16* __restrict__ gamma,
    const __hip_bfloat16* __restrict__ beta,
    void* __restrict__ y, const int* __restrict__ idxl,
    const int* __restrict__ count, int c0,
    int expert, const int* __restrict__ flag)
{
    const int isbf = *flag;
    const int lane = threadIdx.x & 63;
    const int l    = blockIdx.x * 4 + (threadIdx.x >> 6);
    const int cnt  = *count - c0;
    if (l >= cnt) return;
    const int token = idxl[c0 + l];
    const int ch = choice[token];
    const int e0 = ch & 0xFF, e1 = (ch >> 8) & 0xFF;
    const int firstexp = e0 < e1 ? e0 : e1;
    const int accumulate = (expert != firstexp);

    const f32x4* zr = (const f32x4*)(z + (size_t)l * DM);
    f32x4 v[4];
    float sum = 0.f, ssq = 0.f;
    #pragma unroll
    for (int c = 0; c < 4; ++c) {
        f32x4 zv = zr[c * 64 + lane];
        if (isbf) {
            short4 xv = *(const short4*)((const short*)xraw + (size_t)token * DM + c * 256 + lane * 4);
            v[c][0] = zv[0] + bf2f(xv.x);
            v[c][1] = zv[1] + bf2f(xv.y);
            v[c][2] = zv[2] + bf2f(xv.z);
            v[c][3] = zv[3] + bf2f(xv.w);
        } else {
            float4 xv = *(const float4*)((const float*)xraw + (size_t)token * DM + c * 256 + lane * 4);
            v[c][0] = zv[0] + xv.x;
            v[c][1] = zv[1] + xv.y;
            v[c][2] = zv[2] + xv.z;
            v[c][3] = zv[3] + xv.w;
        }
        #pragma unroll
        for (int j = 0; j < 4; ++j) { sum += v[c][j]; ssq += v[c][j] * v[c][j]; }
    }
    #pragma unroll
    for (int off = 32; off > 0; off >>= 1) {
        sum += __shfl_xor(sum, off);
        ssq += __shfl_xor(ssq, off);
    }
    const float mu   = sum * (1.0f / DM);
    const float var  = fmaxf(ssq * (1.0f / DM) - mu * mu, 0.0f);
    const float rstd = rsqrtf(var + 1e-6f);
    const float w    = comb[(size_t)token * 4 + expert];
    #pragma unroll
    for (int c = 0; c < 4; ++c) {
        #pragma unroll
        for (int j = 0; j < 4; ++j) {
            const int id = c * 256 + lane * 4 + j;
            const float g = __bfloat162float(gamma[id]);
            const float b = __bfloat162float(beta[id]);
            float o = w * ((v[c][j] - mu) * rstd * g + b);
            if (isbf) {
                __hip_bfloat16* yr = (__hip_bfloat16*)y + (size_t)token * DM;
                if (accumulate) o += __bfloat162float(yr[id]);
                yr[id] = __float2bfloat16(o);
            } else {
                float* yr = (float*)y + (size_t)token * DM;
                if (accumulate) o += yr[id];
                yr[id] = o;
            }
        }
    }
}

extern "C" void kernel_launch(void* const* d_in, const int* in_sizes, int n_in,
                              void* d_out, int out_size, void* d_ws, size_t ws_size,
                              hipStream_t stream)
{
    char* ws = (char*)d_ws;
    size_t off = 0;
    auto alloc = [&](size_t bytes) -> char* {
        char* p = ws + off;
        off = (off + bytes + 255) & ~(size_t)255;
        return p;
    };
    int*   flag   = (int*)  alloc(256);
    float* comb   = (float*)alloc((size_t)NT * 4 * sizeof(float));
    int*   choice = (int*)  alloc((size_t)NT * sizeof(int));
    int*   counts = (int*)  alloc(NE * sizeof(int));
    int*   idx    = (int*)  alloc((size_t)NE * NT * sizeof(int));
    int*   pos    = (int*)  alloc((size_t)NT * sizeof(int));
    short* b1b    = (short*)alloc((size_t)NE * 2 * DM * 2);
    short* b2b    = (short*)alloc((size_t)NE * DM * 2);
    short* gb     = (short*)alloc((size_t)NE * DM * 2);
    short* bb     = (short*)alloc((size_t)NE * DM * 2);
    short* w1b    = (short*)alloc((size_t)NE * 2 * DM * DM * 2);   // 16 MiB
    short* w2b    = (short*)alloc((size_t)NE * 2 * DM * DM * 2);   // 16 MiB
    short* xb     = (short*)alloc((size_t)NT * DM * 2);            // 32 MiB
    const size_t fixed = off;                                      // ~68 MB

    detect_kernel<<<1, 256, 0, stream>>>((const unsigned int*)d_in[0], flag);
    init_kernel<<<(NE * NT) / 256, 256, 0, stream>>>(counts, idx);

    convert_all_kernel<<<2048, 256, 0, stream>>>(
        (const float*)d_in[0], (const float*)d_in[2], (const float*)d_in[4],
        xb, w1b, w2b, flag);
    convert_small_kernel<<<80, 256, 0, stream>>>(d_in[3], d_in[5], d_in[6], d_in[7],
                                                 b1b, b2b, gb, bb, flag);

    gate_kernel<<<NT / 4, 256, 0, stream>>>(d_in[0], d_in[1], comb, choice, flag);
    route_kernel<<<NT / 256, 256, 0, stream>>>(choice, counts, idx, pos);

    const size_t zBytes = (size_t)2 * NT * DM * sizeof(float);          // 134 MB
    const size_t hFull  = (size_t)(2 * NT + 256) * (2 * DM) * 2;        // 135 MB

    if (fixed + hFull + zBytes + 4096 <= ws_size) {
        // ---- full mode: one dispatch per GEMM, h/z global-compacted ----
        short* h = (short*)alloc(hFull);
        float* z = (float*)alloc(zBytes);
        dim3 g1(2 * DM / 256, NT / 256, NE);        // 8 x 64 x 4 = 2048 blocks
        gemm32<0, 256><<<g1, 512, 0, stream>>>(
            (const short*)d_in[0], xb, (const short*)d_in[2], w1b, b1b,
            (void*)h, idx, counts, 0, 2 * DM, DM, flag, 0, 0);
        dim3 g2(DM / 128, NT / 256, NE);            // 8 x 64 x 4 = 2048 blocks
        gemm32<1, 128><<<g2, 512, 0, stream>>>(
            h, h, (const short*)d_in[4], w2b, b2b,
            (void*)z, idx, counts, 0, DM, 2 * DM, flag, 0, 0);
        ln_fused_kernel<<<NT / 4, 256, 0, stream>>>(z, d_in[0], comb, choice, pos,
                                                    gb, bb, d_out, counts, flag);
        return;
    }

    int R = 0;
    for (int cand = 4096; cand >= 1024; cand >>= 1) {
        const size_t hBytes = (size_t)NE * cand * 2 * DM * 2;
        if (fixed + hBytes + zBytes + 4096 <= ws_size) { R = cand; break; }
    }

    if (R > 0) {
        // ---- chunked mode: h is a 4-expert chunk of R rows each ----
        short* h = (short*)alloc((size_t)NE * R * 2 * DM * 2);
        float* z = (float*)alloc(zBytes);
        for (int c0 = 0; c0 < NT; c0 += R) {
            dim3 g1(2 * DM / 256, R / 256, NE);
            gemm32<0, 256><<<g1, 512, 0, stream>>>(
                (const short*)d_in[0], xb, (const short*)d_in[2], w1b, b1b,
                (void*)h, idx, counts, c0, 2 * DM, DM, flag, 0, R);
            dim3 g2(DM / 128, R / 256, NE);
            gemm32<1, 128><<<g2, 512, 0, stream>>>(
                h, h, (const short*)d_in[4], w2b, b2b,
                (void*)z, idx, counts, c0, DM, 2 * DM, flag, 0, R);
        }
        ln_fused_kernel<<<NT / 4, 256, 0, stream>>>(z, d_in[0], comb, choice, pos,
                                                    gb, bb, d_out, counts, flag);
    } else {
        // ---- workspace-constrained fallback: per-expert chunked ----
        int cap = NT;
        while (cap > 512 && fixed + (size_t)cap * 8192 > ws_size) cap >>= 1;
        short* h = (short*)alloc((size_t)cap * 2 * DM * 2);
        float* z = (float*)alloc((size_t)cap * DM * sizeof(float));
        for (int e = 0; e < NE; ++e) {
            for (int c0 = 0; c0 < NT; c0 += cap) {
                dim3 g1(2 * DM / 256, cap / 256, 1);
                gemm32<0, 256><<<g1, 512, 0, stream>>>(
                    (const short*)d_in[0], xb, (const short*)d_in[2], w1b, b1b,
                    (void*)h, idx, counts, c0, 2 * DM, DM, flag, e, -1);
                dim3 g2(DM / 128, cap / 256, 1);
                gemm32<1, 128><<<g2, 512, 0, stream>>>(
                    h, h, (const short*)d_in[4], w2b, b2b,
                    (void*)z, idx, counts, c0, DM, 2 * DM, flag, e, -1);
                ln_kernel<<<cap / 4, 256, 0, stream>>>(z, d_in[0], comb, choice,
                    (const __hip_bfloat16*)(gb + (size_t)e * DM),
                    (const __hip_bfloat16*)(bb + (size_t)e * DM),
                    d_out, idx + (size_t)e * NT, counts + e, c0, e, flag);
            }
        }
    }
}

// Round 6
// 750.062 us; speedup vs baseline: 1.1776x; 1.1776x over previous
//
#include <hip/hip_runtime.h>
#include <hip/hip_bf16.h>
#include <math.h>

#define NT 16384
#define DM 1024
#define NE 4

typedef __attribute__((ext_vector_type(8))) short short8;  // 8 bf16 (4 VGPRs)
typedef __attribute__((ext_vector_type(4))) float f32x4;

// global -> LDS direct DMA, 16B/lane; LDS dest = wave-uniform base + lane*16
#define GLDS(g, l)                                                        \
  __builtin_amdgcn_global_load_lds(                                       \
      (const __attribute__((address_space(1))) void*)(g),                 \
      (__attribute__((address_space(3))) void*)(l), 16, 0, 0)

__device__ __forceinline__ float bf2f(short h) {
    union { unsigned u; float f; } v;
    v.u = ((unsigned)(unsigned short)h) << 16;
    return v.f;
}

// ============ dtype detection: bf16 vs fp32, from bit statistics of x ========
__global__ __launch_bounds__(256) void detect_kernel(
    const unsigned int* __restrict__ xw, int* __restrict__ flag)
{
    __shared__ int red[4];
    const int t = threadIdx.x;
    int cnt = 0;
    #pragma unroll 4
    for (int i = 0; i < 64; ++i) {
        unsigned w = xw[t * 64 + i];
        unsigned e0 = (w >> 7) & 0xFFu;
        cnt += (e0 >= 100u && e0 <= 150u) ? 1 : 0;
    }
    #pragma unroll
    for (int o = 32; o > 0; o >>= 1) cnt += __shfl_xor(cnt, o);
    if ((t & 63) == 0) red[t >> 6] = cnt;
    __syncthreads();
    if (t == 0) {
        int tot = red[0] + red[1] + red[2] + red[3];
        *flag = (tot > 8192) ? 1 : 0;   // 1 = bf16 inputs, 0 = fp32 inputs
    }
}

// ============ zero idx lists + counts (ws re-poisoned before every call) =====
__global__ __launch_bounds__(256) void init_kernel(
    int* __restrict__ counts, int* __restrict__ idx)
{
    const int t = blockIdx.x * 256 + threadIdx.x;   // 256 blocks -> 65536 = NE*NT
    idx[t] = 0;
    if (t < NE) counts[t] = 0;
}

// ====== fused big converts: x, w1, w2 fp32->bf16 in ONE kernel ==============
__global__ __launch_bounds__(256) void convert_all_kernel(
    const float* __restrict__ x, const float* __restrict__ w1,
    const float* __restrict__ w2,
    short* __restrict__ xb, short* __restrict__ w1b, short* __restrict__ w2b,
    const int* __restrict__ flag)
{
    if (*flag) return;                   // bf16 inputs: consumers read raw ptr
    const int n1 = NT * DM / 4;          // float4 units
    const int n2 = NE * 2 * DM * DM / 4;
    const int total = n1 + 2 * n2;
    const int stride = gridDim.x * blockDim.x;
    for (int i = blockIdx.x * blockDim.x + threadIdx.x; i < total; i += stride) {
        const float4* s; short* d; int j;
        if (i < n1)           { s = (const float4*)x;  d = xb;  j = i; }
        else if (i < n1 + n2) { s = (const float4*)w1; d = w1b; j = i - n1; }
        else                  { s = (const float4*)w2; d = w2b; j = i - n1 - n2; }
        float4 v = s[j];
        __hip_bfloat16 b0 = __float2bfloat16(v.x);
        __hip_bfloat16 b1 = __float2bfloat16(v.y);
        __hip_bfloat16 b2 = __float2bfloat16(v.z);
        __hip_bfloat16 b3 = __float2bfloat16(v.w);
        short4 o;
        o.x = *(short*)&b0; o.y = *(short*)&b1;
        o.z = *(short*)&b2; o.w = *(short*)&b3;
        *(short4*)(d + (size_t)j * 4) = o;
    }
}

// ============ small converts fused: b1(8192) b2(4096) gamma(4096) beta(4096) =
__global__ __launch_bounds__(256) void convert_small_kernel(
    const void* __restrict__ b1, const void* __restrict__ b2,
    const void* __restrict__ ga, const void* __restrict__ be,
    short* __restrict__ b1d, short* __restrict__ b2d,
    short* __restrict__ gad, short* __restrict__ bed,
    const int* __restrict__ flag)
{
    const int isbf = *flag;
    const int t = blockIdx.x * 256 + threadIdx.x;     // 80 blocks = 20480 threads
    const void* src; short* dst; int i;
    if (t < 8192)      { src = b1; dst = b1d; i = t; }
    else if (t < 12288){ src = b2; dst = b2d; i = t - 8192; }
    else if (t < 16384){ src = ga; dst = gad; i = t - 12288; }
    else               { src = be; dst = bed; i = t - 16384; }
    short v;
    if (isbf) v = ((const short*)src)[i];
    else {
        __hip_bfloat16 b = __float2bfloat16(((const float*)src)[i]);
        v = *(short*)&b;
    }
    dst[i] = v;
}

// ======= gate: fp64-acc scores on RAW inputs -> comb[NT,4] + choice[NT] ======
__global__ __launch_bounds__(256) void gate_kernel(
    const void* __restrict__ x, const void* __restrict__ gw,
    float* __restrict__ comb, int* __restrict__ choice,
    const int* __restrict__ flag)
{
    const int lane  = threadIdx.x & 63;
    const int token = blockIdx.x * 4 + (threadIdx.x >> 6);
    double s0 = 0., s1 = 0., s2 = 0., s3 = 0.;
    if (*flag) {
        const short8* xr = (const short8*)((const short*)x + (size_t)token * DM);
        const short8* g0 = (const short8*)((const short*)gw + 0 * DM);
        const short8* g1 = (const short8*)((const short*)gw + 1 * DM);
        const short8* g2 = (const short8*)((const short*)gw + 2 * DM);
        const short8* g3 = (const short8*)((const short*)gw + 3 * DM);
        #pragma unroll
        for (int c = 0; c < 2; ++c) {
            short8 xv = xr[c * 64 + lane];
            short8 a0 = g0[c * 64 + lane], a1 = g1[c * 64 + lane];
            short8 a2 = g2[c * 64 + lane], a3 = g3[c * 64 + lane];
            #pragma unroll
            for (int j = 0; j < 8; ++j) {
                double xd = (double)bf2f(xv[j]);
                s0 += xd * (double)bf2f(a0[j]);
                s1 += xd * (double)bf2f(a1[j]);
                s2 += xd * (double)bf2f(a2[j]);
                s3 += xd * (double)bf2f(a3[j]);
            }
        }
    } else {
        const float4* xr = (const float4*)((const float*)x + (size_t)token * DM);
        const float4* g0 = (const float4*)((const float*)gw + 0 * DM);
        const float4* g1 = (const float4*)((const float*)gw + 1 * DM);
        const float4* g2 = (const float4*)((const float*)gw + 2 * DM);
        const float4* g3 = (const float4*)((const float*)gw + 3 * DM);
        #pragma unroll
        for (int c = 0; c < 4; ++c) {
            float4 xv = xr[c * 64 + lane];
            float4 a0 = g0[c * 64 + lane], a1 = g1[c * 64 + lane];
            float4 a2 = g2[c * 64 + lane], a3 = g3[c * 64 + lane];
            s0 += (double)xv.x * a0.x + (double)xv.y * a0.y + (double)xv.z * a0.z + (double)xv.w * a0.w;
            s1 += (double)xv.x * a1.x + (double)xv.y * a1.y + (double)xv.z * a1.z + (double)xv.w * a1.w;
            s2 += (double)xv.x * a2.x + (double)xv.y * a2.y + (double)xv.z * a2.z + (double)xv.w * a2.w;
            s3 += (double)xv.x * a3.x + (double)xv.y * a3.y + (double)xv.z * a3.z + (double)xv.w * a3.w;
        }
    }
    #pragma unroll
    for (int off = 32; off > 0; off >>= 1) {
        s0 += __shfl_xor(s0, off);
        s1 += __shfl_xor(s1, off);
        s2 += __shfl_xor(s2, off);
        s3 += __shfl_xor(s3, off);
    }
    if (lane == 0) {
        double s[4] = {s0, s1, s2, s3};
        int i1 = 0;
        #pragma unroll
        for (int e = 1; e < 4; ++e) if (s[e] > s[i1]) i1 = e;  // ties -> lowest idx
        int i2 = -1;
        #pragma unroll
        for (int e = 0; e < 4; ++e) {
            if (e == i1) continue;
            if (i2 < 0 || s[e] > s[i2]) i2 = e;
        }
        float e2 = expf((float)(s[i2] - s[i1]));
        float wa = 1.0f / (1.0f + e2);
        float wb = e2 * wa;
        float* cr = comb + (size_t)token * 4;
        #pragma unroll
        for (int e = 0; e < 4; ++e)
            cr[e] = (e == i1) ? wa : ((e == i2) ? wb : 0.0f);
        choice[token] = i1 | (i2 << 8);
    }
}

// ======= route: block-aggregated compaction + per-token list positions =======
__global__ __launch_bounds__(256) void route_kernel(
    const int* __restrict__ choice, int* __restrict__ counts,
    int* __restrict__ idx, int* __restrict__ pos)
{
    __shared__ int T[4][8];     // [wave][k*4+e] per-wave counts
    __shared__ int base[4];
    const int tid = threadIdx.x, w = tid >> 6, lane = tid & 63;
    const int t = blockIdx.x * 256 + tid;
    const int c = choice[t];
    const int e0 = c & 0xFF, e1 = (c >> 8) & 0xFF;
    const unsigned long long lt = ((unsigned long long)1 << lane) - 1;
    int rank0 = 0, rank1 = 0;
    #pragma unroll
    for (int e = 0; e < 4; ++e) {
        unsigned long long m0 = __ballot(e0 == e);
        unsigned long long m1 = __ballot(e1 == e);
        if (e0 == e) rank0 = __popcll(m0 & lt);
        if (e1 == e) rank1 = __popcll(m1 & lt);
        if (lane == 0) { T[w][e] = __popcll(m0); T[w][4 + e] = __popcll(m1); }
    }
    __syncthreads();
    if (tid < 4) {
        int tot = 0;
        #pragma unroll
        for (int w2 = 0; w2 < 4; ++w2) tot += T[w2][tid] + T[w2][4 + tid];
        base[tid] = atomicAdd(&counts[tid], tot);
    }
    __syncthreads();
    int off0 = base[e0], off1 = base[e1];
    #pragma unroll
    for (int w2 = 0; w2 < 4; ++w2) {
        if (w2 < w) off0 += T[w2][e0];
        off1 += T[w2][e1];                   // all k=0 entries precede k=1
        if (w2 < w) off1 += T[w2][4 + e1];
    }
    const int p0 = off0 + rank0;
    const int p1 = off1 + rank1;
    idx[e0 * NT + p0] = t;
    idx[e1 * NT + p1] = t;
    pos[t] = p0 | (p1 << 16);                // position of token in both lists
}

// ====== 128x128 BK=32 GEMM, C = Asel @ B[N,K]^T + bias =======================
// 256 threads (4 waves, 2x2, 64x64 per wave), 32 KiB dbuf LDS,
// __launch_bounds__(256,4) caps VGPR<=128 -> 4 blocks/CU resident.
// Grid 2-4x oversubscribed (1024/512 blocks): independent blocks per CU
// overlap each other's vmcnt+barrier stalls (m114) -- the lever R2-R5's
// 256-block exact-fill lockstep design lacked.
// T2 swizzle (R5-verified, conflicts==0): src pre-XOR (tid&3)^((tid>>3)&3),
// read boff = (quad ^ ((mrow>>1)&3))<<4.  T4 counted vmcnt(4).
// Rarg==0: full mode; Rarg>0: chunked (h at e*Rarg+local, z at prefix+c0);
// Rarg<0: per-expert fallback.
// EPI 0: A rows gathered via idx (x), out bf16 = gelu_exact(acc+bias)  -> h
// EPI 1: A dense rows (h),            out f32  = acc+bias              -> z
template <int EPI>
__global__ __launch_bounds__(256, 4) void gemm128(
    const short* __restrict__ Araw, const short* __restrict__ Acvt,
    const short* __restrict__ Braw, const short* __restrict__ Bcvt,
    const short* __restrict__ biasAll,       // bf16 bits, [NE][N]
    void* __restrict__ Cout,
    const int* __restrict__ idxAll,          // [NE][NT]
    const int* __restrict__ counts,
    int c0, int N, int K, const int* __restrict__ flag,
    int eArg, int Rarg)
{
    // bijective XCD-chunk remap (m204): contiguous chunk per XCD.
    int bx, by, bz;
    {
        int lid = (int)blockIdx.x +
                  (int)gridDim.x * ((int)blockIdx.y + (int)gridDim.y * (int)blockIdx.z);
        const int nwg = (int)(gridDim.x * gridDim.y * gridDim.z);
        if (Rarg >= 0 && (nwg & 7) == 0) {
            const int q = nwg >> 3;
            lid = (lid & 7) * q + (lid >> 3);
        }
        bx = lid % (int)gridDim.x;
        const int rem = lid / (int)gridDim.x;
        by = rem % (int)gridDim.y;
        bz = rem / (int)gridDim.y;
    }

    const int e    = (Rarg < 0) ? eArg : bz;
    const int cnt  = counts[e] - c0;
    const int rowc = by * 128;               // local row of this block
    if (rowc >= cnt) return;                 // block-uniform early exit

    int hRow0 = 0, zRow0 = 0;
    if (Rarg >= 0) {
        int pre = 0;
        #pragma unroll
        for (int i = 0; i < NE; ++i) pre += (i < e) ? counts[i] : 0;
        zRow0 = pre + c0;
        hRow0 = (Rarg == 0) ? pre : e * Rarg;
    }

    const short* A = (*flag) ? Araw : Acvt;  // EPI==1: both point at h
    const short* B = ((*flag) ? Braw : Bcvt) + (size_t)e * 2 * DM * DM;
    const short* bias = biasAll + (size_t)e * N;

    __shared__ __align__(16) short sA[2][4096];   // 128 rows x 32 k
    __shared__ __align__(16) short sB[2][4096];

    const int tid  = threadIdx.x;            // 0..255
    const int wid  = tid >> 6;               // 0..3
    const int col0 = bx * 128;
    const int wm = wid >> 1, wn = wid & 1;   // 2x2 waves, 64x64 each
    const int quad = (tid & 63) >> 4;
    const int mrow = tid & 15;

    // staging unit u: rows [u*64, u*64+64) x 32 k; thread -> row u*64 + tid/4,
    // k8-slot tid&3. Source pre-swizzled: chunk (tid&3)^((tid>>3)&3).
    const int scol = (((tid & 3) ^ ((tid >> 3) & 3)) * 8);
    const short* gA[2];
    const short* gB[2];
    #pragma unroll
    for (int i = 0; i < 2; ++i) {
        const int lr = i * 64 + (tid >> 2);
        size_t grow;
        if (EPI == 0) grow = (size_t)idxAll[(size_t)e * NT + c0 + rowc + lr]; // zero-padded
        else          grow = (size_t)(hRow0 + rowc + lr);
        gA[i] = A + grow * (size_t)K + scol;
        gB[i] = B + (size_t)(col0 + lr) * K + scol;
    }

    f32x4 acc[4][4];
    #pragma unroll
    for (int m = 0; m < 4; ++m)
        #pragma unroll
        for (int n = 0; n < 4; ++n)
            acc[m][n] = (f32x4){0.f, 0.f, 0.f, 0.f};

    auto stage = [&](int buf, int k0) {
        #pragma unroll
        for (int i = 0; i < 2; ++i) {
            GLDS(gA[i] + k0, &sA[buf][i * 2048] + wid * 512);
            GLDS(gB[i] + k0, &sB[buf][i * 2048] + wid * 512);
        }
    };

    const int boff = ((quad ^ ((mrow >> 1) & 3)) << 4);  // read-side slot (bytes)

    const int ntiles = K / 32;
    stage(0, 0);
    int cur = 0;
    for (int t = 0; t < ntiles; ++t) {
        if (t + 1 < ntiles) {
            stage(cur ^ 1, (t + 1) * 32);    // next tile stays in flight
            asm volatile("s_waitcnt vmcnt(4)" ::: "memory");
        } else {
            asm volatile("s_waitcnt vmcnt(0)" ::: "memory");
        }
        __builtin_amdgcn_sched_barrier(0);
        __builtin_amdgcn_s_barrier();        // tile t fully visible
        const char* sAc = (const char*)&sA[cur][0];
        const char* sBc = (const char*)&sB[cur][0];
        short8 a[4], b[4];
        #pragma unroll
        for (int m = 0; m < 4; ++m)
            a[m] = *(const short8*)(sAc + (wm * 64 + m * 16 + mrow) * 64 + boff);
        #pragma unroll
        for (int n = 0; n < 4; ++n)
            b[n] = *(const short8*)(sBc + (wn * 64 + n * 16 + mrow) * 64 + boff);
        #pragma unroll
        for (int m = 0; m < 4; ++m)
            #pragma unroll
            for (int n = 0; n < 4; ++n)
                acc[m][n] = __builtin_amdgcn_mfma_f32_16x16x32_bf16(
                    a[m], b[n], acc[m][n], 0, 0, 0);
        asm volatile("s_waitcnt lgkmcnt(0)" ::: "memory");
        __builtin_amdgcn_sched_barrier(0);
        __builtin_amdgcn_s_barrier();        // reads of buf[cur] closed
        cur ^= 1;
    }

    // epilogue: C/D layout col=lane&15, row=quad*4+reg (m89-verified)
    #pragma unroll
    for (int m = 0; m < 4; ++m) {
        #pragma unroll
        for (int n = 0; n < 4; ++n) {
            const int col = col0 + wn * 64 + n * 16 + mrow;
            const float bval = bf2f(bias[col]);
            #pragma unroll
            for (int i = 0; i < 4; ++i) {
                const int lrow = rowc + wm * 64 + m * 16 + quad * 4 + i;
                if (lrow < cnt) {
                    float v = acc[m][n][i] + bval;
                    if (EPI == 0) {
                        v = 0.5f * v * (1.0f + erff(v * 0.70710678118654752f));
                        ((__hip_bfloat16*)Cout)[(size_t)(hRow0 + lrow) * N + col] =
                            __float2bfloat16(v);
                    } else {
                        ((float*)Cout)[(size_t)(zRow0 + lrow) * N + col] = v;
                    }
                }
            }
        }
    }
}

// ====== fused LN over BOTH experts of a token: y = w0*LN(z0+x) + w1*LN(z1+x) =
__global__ __launch_bounds__(256) void ln_fused_kernel(
    const float* __restrict__ z,               // [2*NT, DM] fp32, prefix layout
    const void* __restrict__ xraw,             // [NT, DM] raw input (bf16/fp32)
    const float* __restrict__ comb,            // [NT, 4]
    const int* __restrict__ choice,            // [NT] packed (i1 | i2<<8)
    const int* __restrict__ pos,               // [NT] packed (p0 | p1<<16)
    const short* __restrict__ gammaAll,        // bf16 bits [NE][DM]
    const short* __restrict__ betaAll,
    void* __restrict__ y,                      // [NT, DM] bf16 or fp32
    const int* __restrict__ counts, const int* __restrict__ flag)
{
    const int isbf = *flag;
    const int lane = threadIdx.x & 63;
    const int t = blockIdx.x * 4 + (threadIdx.x >> 6);

    const int ca = counts[0], cb = counts[1], cc = counts[2];
    const int ch = choice[t];
    const int e0 = ch & 0xFF, e1 = (ch >> 8) & 0xFF;
    const int pp = pos[t];
    const int p0 = pp & 0xFFFF, p1 = (pp >> 16) & 0xFFFF;
    const int b0r = (e0 > 0 ? ca : 0) + (e0 > 1 ? cb : 0) + (e0 > 2 ? cc : 0);
    const int b1r = (e1 > 0 ? ca : 0) + (e1 > 1 ? cb : 0) + (e1 > 2 ? cc : 0);
    const float w0 = comb[(size_t)t * 4 + e0];
    const float w1 = comb[(size_t)t * 4 + e1];

    const f32x4* z0r = (const f32x4*)(z + (size_t)(b0r + p0) * DM);
    const f32x4* z1r = (const f32x4*)(z + (size_t)(b1r + p1) * DM);

    f32x4 v0[4], v1[4];
    float s0 = 0.f, q0 = 0.f, s1 = 0.f, q1 = 0.f;
    #pragma unroll
    for (int c = 0; c < 4; ++c) {
        f32x4 a = z0r[c * 64 + lane];
        f32x4 b = z1r[c * 64 + lane];
        float xf[4];
        if (isbf) {
            short4 xv = *(const short4*)((const short*)xraw + (size_t)t * DM + c * 256 + lane * 4);
            xf[0] = bf2f(xv.x); xf[1] = bf2f(xv.y); xf[2] = bf2f(xv.z); xf[3] = bf2f(xv.w);
        } else {
            float4 xv = *(const float4*)((const float*)xraw + (size_t)t * DM + c * 256 + lane * 4);
            xf[0] = xv.x; xf[1] = xv.y; xf[2] = xv.z; xf[3] = xv.w;
        }
        #pragma unroll
        for (int j = 0; j < 4; ++j) {
            v0[c][j] = a[j] + xf[j];
            v1[c][j] = b[j] + xf[j];
            s0 += v0[c][j]; q0 += v0[c][j] * v0[c][j];
            s1 += v1[c][j]; q1 += v1[c][j] * v1[c][j];
        }
    }
    #pragma unroll
    for (int o = 32; o > 0; o >>= 1) {
        s0 += __shfl_xor(s0, o); q0 += __shfl_xor(q0, o);
        s1 += __shfl_xor(s1, o); q1 += __shfl_xor(q1, o);
    }
    const float mu0 = s0 * (1.0f / DM);
    const float r0  = rsqrtf(fmaxf(q0 * (1.0f / DM) - mu0 * mu0, 0.0f) + 1e-6f);
    const float mu1 = s1 * (1.0f / DM);
    const float r1  = rsqrtf(fmaxf(q1 * (1.0f / DM) - mu1 * mu1, 0.0f) + 1e-6f);

    #pragma unroll
    for (int c = 0; c < 4; ++c) {
        const int id = c * 256 + lane * 4;
        short4 g0v  = *(const short4*)(gammaAll + (size_t)e0 * DM + id);
        short4 be0v = *(const short4*)(betaAll  + (size_t)e0 * DM + id);
        short4 g1v  = *(const short4*)(gammaAll + (size_t)e1 * DM + id);
        short4 be1v = *(const short4*)(betaAll  + (size_t)e1 * DM + id);
        const float g0f[4]  = {bf2f(g0v.x),  bf2f(g0v.y),  bf2f(g0v.z),  bf2f(g0v.w)};
        const float b0f[4]  = {bf2f(be0v.x), bf2f(be0v.y), bf2f(be0v.z), bf2f(be0v.w)};
        const float g1f[4]  = {bf2f(g1v.x),  bf2f(g1v.y),  bf2f(g1v.z),  bf2f(g1v.w)};
        const float b1f[4]  = {bf2f(be1v.x), bf2f(be1v.y), bf2f(be1v.z), bf2f(be1v.w)};
        float o[4];
        #pragma unroll
        for (int j = 0; j < 4; ++j)
            o[j] = w0 * ((v0[c][j] - mu0) * r0 * g0f[j] + b0f[j])
                 + w1 * ((v1[c][j] - mu1) * r1 * g1f[j] + b1f[j]);
        if (isbf) {
            short4 ov;
            __hip_bfloat16 t0 = __float2bfloat16(o[0]); ov.x = *(short*)&t0;
            __hip_bfloat16 t1 = __float2bfloat16(o[1]); ov.y = *(short*)&t1;
            __hip_bfloat16 t2 = __float2bfloat16(o[2]); ov.z = *(short*)&t2;
            __hip_bfloat16 t3 = __float2bfloat16(o[3]); ov.w = *(short*)&t3;
            *(short4*)((short*)y + (size_t)t * DM + id) = ov;
        } else {
            float4 ov = {o[0], o[1], o[2], o[3]};
            *(float4*)((float*)y + (size_t)t * DM + id) = ov;
        }
    }
}

// ====== fallback LN (per-expert, accumulate) — chunked path only =============
__global__ __launch_bounds__(256) void ln_kernel(
    const float* __restrict__ z, const void* __restrict__ xraw,
    const float* __restrict__ comb, const int* __restrict__ choice,
    const __hip_bfloat16* __restrict__ gamma,
    const __hip_bfloat16* __restrict__ beta,
    void* __restrict__ y, const int* __restrict__ idxl,
    const int* __restrict__ count, int c0,
    int expert, const int* __restrict__ flag)
{
    const int isbf = *flag;
    const int lane = threadIdx.x & 63;
    const int l    = blockIdx.x * 4 + (threadIdx.x >> 6);
    const int cnt  = *count - c0;
    if (l >= cnt) return;
    const int token = idxl[c0 + l];
    const int ch = choice[token];
    const int e0 = ch & 0xFF, e1 = (ch >> 8) & 0xFF;
    const int firstexp = e0 < e1 ? e0 : e1;
    const int accumulate = (expert != firstexp);

    const f32x4* zr = (const f32x4*)(z + (size_t)l * DM);
    f32x4 v[4];
    float sum = 0.f, ssq = 0.f;
    #pragma unroll
    for (int c = 0; c < 4; ++c) {
        f32x4 zv = zr[c * 64 + lane];
        if (isbf) {
            short4 xv = *(const short4*)((const short*)xraw + (size_t)token * DM + c * 256 + lane * 4);
            v[c][0] = zv[0] + bf2f(xv.x);
            v[c][1] = zv[1] + bf2f(xv.y);
            v[c][2] = zv[2] + bf2f(xv.z);
            v[c][3] = zv[3] + bf2f(xv.w);
        } else {
            float4 xv = *(const float4*)((const float*)xraw + (size_t)token * DM + c * 256 + lane * 4);
            v[c][0] = zv[0] + xv.x;
            v[c][1] = zv[1] + xv.y;
            v[c][2] = zv[2] + xv.z;
            v[c][3] = zv[3] + xv.w;
        }
        #pragma unroll
        for (int j = 0; j < 4; ++j) { sum += v[c][j]; ssq += v[c][j] * v[c][j]; }
    }
    #pragma unroll
    for (int off = 32; off > 0; off >>= 1) {
        sum += __shfl_xor(sum, off);
        ssq += __shfl_xor(ssq, off);
    }
    const float mu   = sum * (1.0f / DM);
    const float var  = fmaxf(ssq * (1.0f / DM) - mu * mu, 0.0f);
    const float rstd = rsqrtf(var + 1e-6f);
    const float w    = comb[(size_t)token * 4 + expert];
    #pragma unroll
    for (int c = 0; c < 4; ++c) {
        #pragma unroll
        for (int j = 0; j < 4; ++j) {
            const int id = c * 256 + lane * 4 + j;
            const float g = __bfloat162float(gamma[id]);
            const float b = __bfloat162float(beta[id]);
            float o = w * ((v[c][j] - mu) * rstd * g + b);
            if (isbf) {
                __hip_bfloat16* yr = (__hip_bfloat16*)y + (size_t)token * DM;
                if (accumulate) o += __bfloat162float(yr[id]);
                yr[id] = __float2bfloat16(o);
            } else {
                float* yr = (float*)y + (size_t)token * DM;
                if (accumulate) o += yr[id];
                yr[id] = o;
            }
        }
    }
}

extern "C" void kernel_launch(void* const* d_in, const int* in_sizes, int n_in,
                              void* d_out, int out_size, void* d_ws, size_t ws_size,
                              hipStream_t stream)
{
    char* ws = (char*)d_ws;
    size_t off = 0;
    auto alloc = [&](size_t bytes) -> char* {
        char* p = ws + off;
        off = (off + bytes + 255) & ~(size_t)255;
        return p;
    };
    int*   flag   = (int*)  alloc(256);
    float* comb   = (float*)alloc((size_t)NT * 4 * sizeof(float));
    int*   choice = (int*)  alloc((size_t)NT * sizeof(int));
    int*   counts = (int*)  alloc(NE * sizeof(int));
    int*   idx    = (int*)  alloc((size_t)NE * NT * sizeof(int));
    int*   pos    = (int*)  alloc((size_t)NT * sizeof(int));
    short* b1b    = (short*)alloc((size_t)NE * 2 * DM * 2);
    short* b2b    = (short*)alloc((size_t)NE * DM * 2);
    short* gb     = (short*)alloc((size_t)NE * DM * 2);
    short* bb     = (short*)alloc((size_t)NE * DM * 2);
    short* w1b    = (short*)alloc((size_t)NE * 2 * DM * DM * 2);   // 16 MiB
    short* w2b    = (short*)alloc((size_t)NE * 2 * DM * DM * 2);   // 16 MiB
    short* xb     = (short*)alloc((size_t)NT * DM * 2);            // 32 MiB
    const size_t fixed = off;                                      // ~68 MB

    detect_kernel<<<1, 256, 0, stream>>>((const unsigned int*)d_in[0], flag);
    init_kernel<<<(NE * NT) / 256, 256, 0, stream>>>(counts, idx);

    convert_all_kernel<<<2048, 256, 0, stream>>>(
        (const float*)d_in[0], (const float*)d_in[2], (const float*)d_in[4],
        xb, w1b, w2b, flag);
    convert_small_kernel<<<80, 256, 0, stream>>>(d_in[3], d_in[5], d_in[6], d_in[7],
                                                 b1b, b2b, gb, bb, flag);

    gate_kernel<<<NT / 4, 256, 0, stream>>>(d_in[0], d_in[1], comb, choice, flag);
    route_kernel<<<NT / 256, 256, 0, stream>>>(choice, counts, idx, pos);

    const size_t zBytes = (size_t)2 * NT * DM * sizeof(float);          // 134 MB
    const size_t hFull  = (size_t)(2 * NT + 128) * (2 * DM) * 2;        // 135 MB

    if (fixed + hFull + zBytes + 4096 <= ws_size) {
        // ---- full mode: one dispatch per GEMM, h/z global-compacted ----
        short* h = (short*)alloc(hFull);
        float* z = (float*)alloc(zBytes);
        dim3 g1(2 * DM / 128, NT / 128, NE);        // 16 x 128 x 4
        gemm128<0><<<g1, 256, 0, stream>>>(
            (const short*)d_in[0], xb, (const short*)d_in[2], w1b, b1b,
            (void*)h, idx, counts, 0, 2 * DM, DM, flag, 0, 0);
        dim3 g2(DM / 128, NT / 128, NE);            // 8 x 128 x 4
        gemm128<1><<<g2, 256, 0, stream>>>(
            h, h, (const short*)d_in[4], w2b, b2b,
            (void*)z, idx, counts, 0, DM, 2 * DM, flag, 0, 0);
        ln_fused_kernel<<<NT / 4, 256, 0, stream>>>(z, d_in[0], comb, choice, pos,
                                                    gb, bb, d_out, counts, flag);
        return;
    }

    int R = 0;
    for (int cand = 4096; cand >= 1024; cand >>= 1) {
        const size_t hBytes = (size_t)NE * cand * 2 * DM * 2;
        if (fixed + hBytes + zBytes + 4096 <= ws_size) { R = cand; break; }
    }

    if (R > 0) {
        // ---- chunked mode: h is a 4-expert chunk of R rows each ----
        // R=2048 -> gemm1 grid 16x16x4 = 1024 blocks (4/CU), gemm2 512 (2/CU)
        short* h = (short*)alloc((size_t)NE * R * 2 * DM * 2);
        float* z = (float*)alloc(zBytes);
        for (int c0 = 0; c0 < NT; c0 += R) {
            dim3 g1(2 * DM / 128, R / 128, NE);
            gemm128<0><<<g1, 256, 0, stream>>>(
                (const short*)d_in[0], xb, (const short*)d_in[2], w1b, b1b,
                (void*)h, idx, counts, c0, 2 * DM, DM, flag, 0, R);
            dim3 g2(DM / 128, R / 128, NE);
            gemm128<1><<<g2, 256, 0, stream>>>(
                h, h, (const short*)d_in[4], w2b, b2b,
                (void*)z, idx, counts, c0, DM, 2 * DM, flag, 0, R);
        }
        ln_fused_kernel<<<NT / 4, 256, 0, stream>>>(z, d_in[0], comb, choice, pos,
                                                    gb, bb, d_out, counts, flag);
    } else {
        // ---- workspace-constrained fallback: per-expert chunked ----
        int cap = NT;
        while (cap > 512 && fixed + (size_t)cap * 8192 > ws_size) cap >>= 1;
        short* h = (short*)alloc((size_t)cap * 2 * DM * 2);
        float* z = (float*)alloc((size_t)cap * DM * sizeof(float));
        for (int e = 0; e < NE; ++e) {
            for (int c0 = 0; c0 < NT; c0 += cap) {
                dim3 g1(2 * DM / 128, cap / 128, 1);
                gemm128<0><<<g1, 256, 0, stream>>>(
                    (const short*)d_in[0], xb, (const short*)d_in[2], w1b, b1b,
                    (void*)h, idx, counts, c0, 2 * DM, DM, flag, e, -1);
                dim3 g2(DM / 128, cap / 128, 1);
                gemm128<1><<<g2, 256, 0, stream>>>(
                    h, h, (const short*)d_in[4], w2b, b2b,
                    (void*)z, idx, counts, c0, DM, 2 * DM, flag, e, -1);
                ln_kernel<<<cap / 4, 256, 0, stream>>>(z, d_in[0], comb, choice,
                    (const __hip_bfloat16*)(gb + (size_t)e * DM),
                    (const __hip_bfloat16*)(bb + (size_t)e * DM),
                    d_out, idx + (size_t)e * NT, counts + e, c0, e, flag);
            }
        }
    }
}